// Round 8
// baseline (260.014 us; speedup 1.0000x reference)
//
#include <hip/hip_runtime.h>

// MultipleKmeans: T=16384 frames, E=1024, M=8 models, K=512 clusters.
// Round 12: ABLATION ROUND, v2. Pipeline is byte-identical R10 (196.4us
// best). R11's probe core-dumped; v2 removes both risk surfaces:
//   - B-pattern loads read CENT (pure input, same 2^17-stride byte
//     pattern, max offset 16.66MB < 16.78MB) instead of out.
//   - NO global writes: keep-alive via asm volatile (DCE-proof).
// Probe p_nob = k_dist's GEMM core (grid/LDS/barriers/A-chain identical)
// with the B ring loaded once, never refilled; 2 passes over 8 chunks.
// Precommit: C = dur(p_nob)/2. C>=20us -> core is the wall (R13 attacks
// core). C<=12us -> B-reload path is the wall (R13 pads panel stride).
//
// ws layout (<=100416 B):
//   [     0, 32768): double csq64[M*K]
//   [ 32768, 34816): int    hist[64][8]
//   [ 34816, 34880): int    offs[9]
//   [ 34880,100416): int    order[T]

#define T_FRAMES 16384
#define E_DIM    1024
#define M_MODELS 8
#define K_CLUST  512

#define FPB 32     // frames per k_dist block
#define NCH 8      // K chunks of 128

typedef __bf16 bf16x8 __attribute__((ext_vector_type(8)));
typedef float  floatx16 __attribute__((ext_vector_type(16)));

__device__ __forceinline__ bf16x8 cvt8(const float4 a, const float4 b) {
  bf16x8 h;
  h[0] = (__bf16)a.x; h[1] = (__bf16)a.y; h[2] = (__bf16)a.z; h[3] = (__bf16)a.w;
  h[4] = (__bf16)b.x; h[5] = (__bf16)b.y; h[6] = (__bf16)b.z; h[7] = (__bf16)b.w;
  return h;
}

// ------- K0: cent fp32 -> swizzled bf16 (+csq64) + hist (blocks 0..63) -----
__global__ __launch_bounds__(256) void k_cvt(const float* __restrict__ cent,
                                             float* __restrict__ out,
                                             double* __restrict__ csq64,
                                             const int* __restrict__ midx,
                                             int* __restrict__ hist) {
  const int b = blockIdx.x;              // 512 blocks
  const int m = b >> 6;
  const int cg = (b >> 2) & 15;
  const int q = b & 3;
  const int tid = threadIdx.x;
  const int ci = tid & 31;
  const int t8 = tid >> 5;               // 0..7
  const int gk0 = q * 32 + t8 * 4;
  const int B32 = (m * 16 + cg) * 32;
  const float* src = cent + ((size_t)(m * K_CLUST + cg * 32 + ci)) * E_DIM;
  double ss = 0.0;
#pragma unroll
  for (int j = 0; j < 4; ++j) {
    const int gk = gk0 + j;
    const float4 a = *(const float4*)(src + gk * 8);
    const float4 bb = *(const float4*)(src + gk * 8 + 4);
    ss += (double)a.x * a.x + (double)a.y * a.y + (double)a.z * a.z +
          (double)a.w * a.w + (double)bb.x * bb.x + (double)bb.y * bb.y +
          (double)bb.z * bb.z + (double)bb.w * bb.w;
    const size_t foff = (size_t)(B32 + (gk >> 2)) * 1024 + 512 +
                        ((gk & 3) * 32 + ci) * 4;
    *(bf16x8*)(out + foff) = cvt8(a, bb);
  }
  __shared__ double csq_l[32][8];
  csq_l[ci][t8] = ss;
  __syncthreads();
  if (tid < 32) {
    double s = 0.0;
#pragma unroll
    for (int t = 0; t < 8; ++t) s += csq_l[tid][t];
    atomicAdd(&csq64[m * K_CLUST + cg * 32 + tid], s);
  }
  // ---- fused per-segment model histogram (blocks 0..63 only) ----
  if (b < 64) {
    __shared__ int h[M_MODELS * 33];
    for (int i = tid; i < M_MODELS * 33; i += 256) h[i] = 0;
    __syncthreads();
    const int mm = midx[b * 256 + tid];
    atomicAdd(&h[mm * 33 + (tid & 31)], 1);
    __syncthreads();
    if (tid < M_MODELS) {
      int s = 0;
      for (int j = 0; j < 32; ++j) s += h[tid * 33 + j];
      hist[b * M_MODELS + tid] = s;
    }
  }
}

// ---------------- K2: scatter frames into per-model buckets ----------------
__global__ __launch_bounds__(256) void k_scatter(const int* __restrict__ midx,
                                                 const int* __restrict__ hist,
                                                 int* __restrict__ order,
                                                 int* __restrict__ offs) {
  __shared__ int h2[64 * M_MODELS];
  __shared__ int cur[M_MODELS];
  const int tid = threadIdx.x;
  h2[tid] = hist[tid];
  h2[tid + 256] = hist[tid + 256];
  __syncthreads();
  if (tid < M_MODELS) {
    int tot_before = 0;
    for (int mp = 0; mp < tid; ++mp)
      for (int b = 0; b < 64; ++b) tot_before += h2[b * M_MODELS + mp];
    int prior = 0;
    for (int b = 0; b < (int)blockIdx.x; ++b) prior += h2[b * M_MODELS + tid];
    cur[tid] = tot_before + prior;
  }
  if (blockIdx.x == 0 && tid <= M_MODELS) {
    int o = 0;
    for (int mp = 0; mp < tid; ++mp)
      for (int b = 0; b < 64; ++b) o += h2[b * M_MODELS + mp];
    offs[tid] = o;
  }
  __syncthreads();
  const int f = blockIdx.x * 256 + tid;
  const int pos = atomicAdd(&cur[midx[f]], 1);
  order[pos] = f;
}

// ---------------- K3: fused scores + argmin + recheck -> code/output -------
// (identical to R10)
__global__ __launch_bounds__(512, 2) void k_dist(const float* __restrict__ emb,
                                                 const float* __restrict__ cent,
                                                 const double* __restrict__ csq64,
                                                 const int* __restrict__ order,
                                                 const int* __restrict__ offs,
                                                 float* __restrict__ out) {
  const int m = blockIdx.x;
  const int o0 = offs[m];
  const int cnt = offs[m + 1] - o0;
  const int start = blockIdx.y * FPB;
  if (start >= cnt) return;
  const int nvalid = min(FPB, cnt - start);

  __shared__ __align__(16) __bf16 A_l[2 * 16 * FPB * 8];  // 16 KB
  __shared__ int rows_l[FPB];
  __shared__ float wmin_s[8][FPB];
  __shared__ int wcol_s[8][FPB];
  __shared__ float gmin_s[FPB];
  __shared__ int cnt_s[FPB];
  __shared__ int cand_s[FPB][32];

  const int tid = threadIdx.x;
  const int l = tid & 63;
  const int w = tid >> 6;          // 0..7
  const int ln = l & 31;
  const int lh = l >> 5;

  if (tid < FPB) rows_l[tid] = order[o0 + start + min(tid, nvalid - 1)];
  __syncthreads();

  const int s_row = tid & 31;
  const int s_g = tid >> 5;                      // 0..15
  const float4* emb4 = (const float4*)emb;
  const size_t arow4 = (size_t)rows_l[s_row] * (E_DIM / 4);

  float4 pa[2];
  pa[0] = emb4[arow4 + s_g * 2 + 0];
  pa[1] = emb4[arow4 + s_g * 2 + 1];
  *(bf16x8*)(A_l + ((s_g)*FPB + s_row) * 8) = cvt8(pa[0], pa[1]);

  const char* bbase[2];
#pragma unroll
  for (int ct = 0; ct < 2; ++ct) {
    const int cg = w * 2 + ct;
    bbase[ct] = (const char*)out + (size_t)(m * 16 + cg) * 131072 + 2048 + l * 16;
  }
#define LOADB(ct, kb) (*(const bf16x8*)(bbase[ct] + (((kb) >> 1) << 12) + (((kb) & 1) << 10)))

  bf16x8 bR[8][2];                               // depth-8 ring
#pragma unroll
  for (int d = 0; d < 8; ++d)
#pragma unroll
    for (int ct = 0; ct < 2; ++ct) bR[d][ct] = LOADB(ct, d);

  floatx16 acc[2] = {};

  for (int c = 0; c < NCH; ++c) {
    __syncthreads();                             // A buf (c&1) ready
    const int buf = (c & 1) * 16;
    if (c + 1 < NCH) {
      pa[0] = emb4[arow4 + (c + 1) * 32 + s_g * 2 + 0];
      pa[1] = emb4[arow4 + (c + 1) * 32 + s_g * 2 + 1];
    }
#pragma unroll
    for (int jj = 0; jj < 8; ++jj) {
      const int kb = c * 8 + jj;
      const int p = kb & 7;
      const bf16x8 a0 = *(const bf16x8*)(A_l + ((buf + jj * 2 + lh) * FPB + ln) * 8);
      acc[0] = __builtin_amdgcn_mfma_f32_32x32x16_bf16(a0, bR[p][0], acc[0], 0, 0, 0);
      acc[1] = __builtin_amdgcn_mfma_f32_32x32x16_bf16(a0, bR[p][1], acc[1], 0, 0, 0);
      if (kb + 8 < 64) {
        bR[p][0] = LOADB(0, kb + 8);
        bR[p][1] = LOADB(1, kb + 8);
      }
    }
    if (c + 1 < NCH) {                           // write other buffer
      const int nbuf = ((c + 1) & 1) * 16;
      *(bf16x8*)(A_l + ((nbuf + s_g) * FPB + s_row) * 8) = cvt8(pa[0], pa[1]);
    }
  }
#undef LOADB

  float cs[2];
#pragma unroll
  for (int ct = 0; ct < 2; ++ct)
    cs[ct] = (float)csq64[m * K_CLUST + w * 64 + ct * 32 + ln];

#pragma unroll
  for (int r = 0; r < 16; ++r) {
    const int fr = (r & 3) + 8 * (r >> 2) + 4 * lh;
    float bm = cs[0] - 2.0f * acc[0][r];
    int bc = w * 64 + ln;
    {
      const float s = cs[1] - 2.0f * acc[1][r];
      if (s < bm) { bm = s; bc = w * 64 + 32 + ln; }
    }
#pragma unroll
    for (int sh = 1; sh <= 16; sh <<= 1) {
      const float om = __shfl_xor(bm, sh, 64);
      const int oc = __shfl_xor(bc, sh, 64);
      if (om < bm || (om == bm && oc < bc)) { bm = om; bc = oc; }
    }
    if (ln == 0) { wmin_s[w][fr] = bm; wcol_s[w][fr] = bc; }
  }
  __syncthreads();

  if (tid < FPB) {
    float g = wmin_s[0][tid];
    int gc = wcol_s[0][tid];
#pragma unroll
    for (int w2 = 1; w2 < 8; ++w2) {
      const float v = wmin_s[w2][tid];
      const int vc = wcol_s[w2][tid];
      if (v < g || (v == g && vc < gc)) { g = v; gc = vc; }
    }
    gmin_s[tid] = g;
    cnt_s[tid] = 0;
  }
  __syncthreads();

#pragma unroll
  for (int r = 0; r < 16; ++r) {
    const int fr = (r & 3) + 8 * (r >> 2) + 4 * lh;
    const float thr = gmin_s[fr] + 3.0f;
#pragma unroll
    for (int ct = 0; ct < 2; ++ct) {
      const float s = cs[ct] - 2.0f * acc[ct][r];
      if (s < thr) {
        const int ix = atomicAdd(&cnt_s[fr], 1);
        if (ix < 32) cand_s[fr][ix] = w * 64 + ct * 32 + ln;
      }
    }
  }
  __syncthreads();

  for (int i = 0; i < 4; ++i) {
    const int f = w * 4 + i;
    const int t = rows_l[f];
    const int n = min(cnt_s[f], 32);
    int code;
    if (n == 1) {
      code = cand_s[f][0];
    } else {
      float4 xv[4];
#pragma unroll
      for (int q = 0; q < 4; ++q) xv[q] = emb4[(size_t)t * (E_DIM / 4) + q * 64 + l];
      double bd = 1e300;
      int bi = 1 << 30;
      for (int j = 0; j < n; ++j) {
        const int cc = cand_s[f][j];
        const float4* crow4 = (const float4*)(cent + ((size_t)(m * K_CLUST + cc)) * E_DIM);
        double s = 0.0;
#pragma unroll
        for (int q = 0; q < 4; ++q) {
          const float4 cv = crow4[q * 64 + l];
          s += (double)xv[q].x * cv.x + (double)xv[q].y * cv.y +
               (double)xv[q].z * cv.z + (double)xv[q].w * cv.w;
        }
#pragma unroll
        for (int sh = 32; sh >= 1; sh >>= 1) s += __shfl_xor(s, sh, 64);
        const double d = csq64[m * K_CLUST + cc] - 2.0 * s;
        if (d < bd || (d == bd && cc < bi)) { bd = d; bi = cc; }
      }
      code = bi;
    }
    if (t >= 4096) {
      const float4* crow = (const float4*)(cent + ((size_t)(m * K_CLUST + code)) * E_DIM);
      float4* drow = (float4*)(out + (size_t)t * E_DIM);
#pragma unroll
      for (int q = 0; q < 4; ++q) drow[q * 64 + l] = crow[q * 64 + l];
    } else if (l == 0) {
      *(int*)(out + (size_t)t * E_DIM) = code;
    }
  }
}

// ---------------- K4: expand parked codes (t < 4096) -> output rows --------
__global__ __launch_bounds__(256) void k_gather(const float* __restrict__ cent,
                                                const int* __restrict__ midx,
                                                float* __restrict__ out) {
  const int t = blockIdx.x * 4 + (threadIdx.x >> 6);   // t in [0, 4096)
  const int l = threadIdx.x & 63;
  float* drow = out + (size_t)t * E_DIM;
  const int code = *(const int*)drow;
  const int m = midx[t];
  const float4* src = (const float4*)(cent + ((size_t)(m * K_CLUST + code)) * E_DIM);
  float4* dst = (float4*)drow;
#pragma unroll
  for (int q = 0; q < 4; ++q) dst[q * 64 + l] = src[q * 64 + l];
}

// ---------------- PROBE v2: core WITHOUT B refills, 2 passes, no writes ----
// Identical grid/block/LDS/barrier/A-prefetch structure to k_dist's main
// loop. B ring loaded ONCE from cent (same byte-offset pattern as the real
// B panels: (m*16+cg)*2^17 + 2048 + ..., max 16.66MB < cent's 16.78MB) and
// never refilled. 2 passes x 8 chunks; A global loads re-issued per chunk.
// NO global writes: accumulators kept live via asm volatile.
__global__ __launch_bounds__(512, 2) void p_nob(const float* __restrict__ emb,
                                                const int* __restrict__ order,
                                                const int* __restrict__ offs,
                                                const float* __restrict__ centRO) {
  const int m = blockIdx.x;
  const int o0 = offs[m];
  const int cnt = offs[m + 1] - o0;
  const int start = blockIdx.y * FPB;
  if (start >= cnt) return;
  const int nvalid = min(FPB, cnt - start);

  __shared__ __align__(16) __bf16 A_l[2 * 16 * FPB * 8];  // 16 KB
  __shared__ int rows_l[FPB];

  const int tid = threadIdx.x;
  const int l = tid & 63;
  const int w = tid >> 6;
  const int ln = l & 31;
  const int lh = l >> 5;

  if (tid < FPB) rows_l[tid] = order[o0 + start + min(tid, nvalid - 1)];
  __syncthreads();

  const int s_row = tid & 31;
  const int s_g = tid >> 5;
  const float4* emb4 = (const float4*)emb;
  const size_t arow4 = (size_t)rows_l[s_row] * (E_DIM / 4);

  float4 pa[2];
  pa[0] = emb4[arow4 + s_g * 2 + 0];
  pa[1] = emb4[arow4 + s_g * 2 + 1];
  *(bf16x8*)(A_l + ((s_g)*FPB + s_row) * 8) = cvt8(pa[0], pa[1]);

  const char* bbase[2];
#pragma unroll
  for (int ct = 0; ct < 2; ++ct) {
    const int cg = w * 2 + ct;
    bbase[ct] = (const char*)centRO + (size_t)(m * 16 + cg) * 131072 + 2048 + l * 16;
  }
#define LOADB(ct, kb) (*(const bf16x8*)(bbase[ct] + (((kb) >> 1) << 12) + (((kb) & 1) << 10)))
  bf16x8 bR[8][2];
#pragma unroll
  for (int d = 0; d < 8; ++d)
#pragma unroll
    for (int ct = 0; ct < 2; ++ct) bR[d][ct] = LOADB(ct, d);
#undef LOADB

  floatx16 acc[2] = {};

  for (int cc = 0; cc < 2 * NCH; ++cc) {         // 2 passes x 8 chunks
    __syncthreads();
    const int buf = (cc & 1) * 16;
    {
      const int nchunk = (cc + 1) & 7;           // wrap A addresses
      pa[0] = emb4[arow4 + nchunk * 32 + s_g * 2 + 0];
      pa[1] = emb4[arow4 + nchunk * 32 + s_g * 2 + 1];
    }
#pragma unroll
    for (int jj = 0; jj < 8; ++jj) {
      const bf16x8 a0 = *(const bf16x8*)(A_l + ((buf + jj * 2 + lh) * FPB + ln) * 8);
      acc[0] = __builtin_amdgcn_mfma_f32_32x32x16_bf16(a0, bR[jj][0], acc[0], 0, 0, 0);
      acc[1] = __builtin_amdgcn_mfma_f32_32x32x16_bf16(a0, bR[jj][1], acc[1], 0, 0, 0);
    }
    if (cc + 1 < 2 * NCH) {
      const int nbuf = ((cc + 1) & 1) * 16;
      *(bf16x8*)(A_l + ((nbuf + s_g) * FPB + s_row) * 8) = cvt8(pa[0], pa[1]);
    }
  }

  // keep-alive: no memory writes; pin every accumulator register live.
  float s = 0.f;
#pragma unroll
  for (int r = 0; r < 16; ++r) s += acc[0][r] + acc[1][r];
  asm volatile("" :: "v"(s));
}

extern "C" void kernel_launch(void* const* d_in, const int* in_sizes, int n_in,
                              void* d_out, int out_size, void* d_ws, size_t ws_size,
                              hipStream_t stream) {
  const float* emb = (const float*)d_in[0];     // [1,T,E] fp32
  const float* cent = (const float*)d_in[1];    // [M,K,E] fp32
  const int* midx = (const int*)d_in[2];        // [T] int32
  float* out = (float*)d_out;                   // [1,T,E] fp32

  char* ws = (char*)d_ws;                       // ~100 KB
  double* csq64 = (double*)(ws + 0);
  int* hist = (int*)(ws + 32768);
  int* offs = (int*)(ws + 34816);
  int* order = (int*)(ws + 34880);

  hipMemsetAsync(csq64, 0, M_MODELS * K_CLUST * sizeof(double), stream);
  hipLaunchKernelGGL(k_cvt, dim3(512), dim3(256), 0, stream,
                     cent, out, csq64, midx, hist);
  hipLaunchKernelGGL(k_scatter, dim3(64), dim3(256), 0, stream, midx, hist, order, offs);
  hipLaunchKernelGGL(k_dist, dim3(M_MODELS, 80), dim3(512), 0, stream,
                     emb, cent, csq64, order, offs, out);
  hipLaunchKernelGGL(k_gather, dim3(4096 / 4), dim3(256), 0, stream,
                     cent, midx, out);
  // ---- ablation probe: reads inputs only, writes nothing ----
  hipLaunchKernelGGL(p_nob, dim3(M_MODELS, 80), dim3(512), 0, stream,
                     emb, order, offs, cent);
}

// Round 9
// 209.331 us; speedup vs baseline: 1.2421x; 1.2421x over previous
//
#include <hip/hip_runtime.h>

// MultipleKmeans: T=16384 frames, E=1024, M=8 models, K=512 clusters.
// Round 13: NCH 8 -> 2 in k_dist. R12's probe measured the barrier-chained
// core (no B refills) at ~30us/pass: each chunk's vmcnt(0)-before-barrier
// drain exposes a full HBM round trip for the 32-random-row A gather, and
// the 8-step jj loop (~250cy) is too short to hide it. 8 drains/block.
// Fix: chunk = 512 k-floats (A dbuf 2x32KB LDS, 70.5KB total), jj loop =
// 32 steps (~1200+cy) hides next-chunk A prefetch + B-refill pipeline;
// only 2 drains/block. Depth-8 B ring kept. launch_bounds(512,2) ->
// 256-VGPR cap for the 8-float4 staging regs. Rest identical to R10.
//
// ws layout (<=100416 B):
//   [     0, 32768): double csq64[M*K]
//   [ 32768, 34816): int    hist[64][8]
//   [ 34816, 34880): int    offs[9]
//   [ 34880,100416): int    order[T]

#define T_FRAMES 16384
#define E_DIM    1024
#define M_MODELS 8
#define K_CLUST  512

#define FPB 32     // frames per k_dist block
#define NCH 2      // K chunks of 512 floats

typedef __bf16 bf16x8 __attribute__((ext_vector_type(8)));
typedef float  floatx16 __attribute__((ext_vector_type(16)));

__device__ __forceinline__ bf16x8 cvt8(const float4 a, const float4 b) {
  bf16x8 h;
  h[0] = (__bf16)a.x; h[1] = (__bf16)a.y; h[2] = (__bf16)a.z; h[3] = (__bf16)a.w;
  h[4] = (__bf16)b.x; h[5] = (__bf16)b.y; h[6] = (__bf16)b.z; h[7] = (__bf16)b.w;
  return h;
}

// ------- K0: cent fp32 -> swizzled bf16 (+csq64) + hist (blocks 0..63) -----
__global__ __launch_bounds__(256) void k_cvt(const float* __restrict__ cent,
                                             float* __restrict__ out,
                                             double* __restrict__ csq64,
                                             const int* __restrict__ midx,
                                             int* __restrict__ hist) {
  const int b = blockIdx.x;              // 512 blocks
  const int m = b >> 6;
  const int cg = (b >> 2) & 15;
  const int q = b & 3;
  const int tid = threadIdx.x;
  const int ci = tid & 31;
  const int t8 = tid >> 5;               // 0..7
  const int gk0 = q * 32 + t8 * 4;
  const int B32 = (m * 16 + cg) * 32;
  const float* src = cent + ((size_t)(m * K_CLUST + cg * 32 + ci)) * E_DIM;
  double ss = 0.0;
#pragma unroll
  for (int j = 0; j < 4; ++j) {
    const int gk = gk0 + j;
    const float4 a = *(const float4*)(src + gk * 8);
    const float4 bb = *(const float4*)(src + gk * 8 + 4);
    ss += (double)a.x * a.x + (double)a.y * a.y + (double)a.z * a.z +
          (double)a.w * a.w + (double)bb.x * bb.x + (double)bb.y * bb.y +
          (double)bb.z * bb.z + (double)bb.w * bb.w;
    const size_t foff = (size_t)(B32 + (gk >> 2)) * 1024 + 512 +
                        ((gk & 3) * 32 + ci) * 4;
    *(bf16x8*)(out + foff) = cvt8(a, bb);
  }
  __shared__ double csq_l[32][8];
  csq_l[ci][t8] = ss;
  __syncthreads();
  if (tid < 32) {
    double s = 0.0;
#pragma unroll
    for (int t = 0; t < 8; ++t) s += csq_l[tid][t];
    atomicAdd(&csq64[m * K_CLUST + cg * 32 + tid], s);
  }
  // ---- fused per-segment model histogram (blocks 0..63 only) ----
  if (b < 64) {
    __shared__ int h[M_MODELS * 33];
    for (int i = tid; i < M_MODELS * 33; i += 256) h[i] = 0;
    __syncthreads();
    const int mm = midx[b * 256 + tid];
    atomicAdd(&h[mm * 33 + (tid & 31)], 1);
    __syncthreads();
    if (tid < M_MODELS) {
      int s = 0;
      for (int j = 0; j < 32; ++j) s += h[tid * 33 + j];
      hist[b * M_MODELS + tid] = s;
    }
  }
}

// ---------------- K2: scatter frames into per-model buckets ----------------
__global__ __launch_bounds__(256) void k_scatter(const int* __restrict__ midx,
                                                 const int* __restrict__ hist,
                                                 int* __restrict__ order,
                                                 int* __restrict__ offs) {
  __shared__ int h2[64 * M_MODELS];
  __shared__ int cur[M_MODELS];
  const int tid = threadIdx.x;
  h2[tid] = hist[tid];
  h2[tid + 256] = hist[tid + 256];
  __syncthreads();
  if (tid < M_MODELS) {
    int tot_before = 0;
    for (int mp = 0; mp < tid; ++mp)
      for (int b = 0; b < 64; ++b) tot_before += h2[b * M_MODELS + mp];
    int prior = 0;
    for (int b = 0; b < (int)blockIdx.x; ++b) prior += h2[b * M_MODELS + tid];
    cur[tid] = tot_before + prior;
  }
  if (blockIdx.x == 0 && tid <= M_MODELS) {
    int o = 0;
    for (int mp = 0; mp < tid; ++mp)
      for (int b = 0; b < 64; ++b) o += h2[b * M_MODELS + mp];
    offs[tid] = o;
  }
  __syncthreads();
  const int f = blockIdx.x * 256 + tid;
  const int pos = atomicAdd(&cur[midx[f]], 1);
  order[pos] = f;
}

// ---------------- K3: fused scores + argmin + recheck -> code/output -------
// Block: 8 waves (512 thr), tile = 32 frames x 512 cols; wave w -> cols
// [w*64, w*64+64). acc: 2 x 32x32 tiles. A: TWO chunks of 512 k, LDS
// double-buffered (64 KB); chunk-1 loads issued before chunk-0's 32-step
// MFMA loop (latency hidden). B: swizzled bf16 (d_out rows 0..4095 high
// halves), depth-8 register ring, refills consumed within-chunk.
// Only 2 barrier/vmcnt drains per block (was 8).
// Resolution: t>=4096 -> direct row write; t<4096 -> park code at col 0.
__global__ __launch_bounds__(512, 2) void k_dist(const float* __restrict__ emb,
                                                 const float* __restrict__ cent,
                                                 const double* __restrict__ csq64,
                                                 const int* __restrict__ order,
                                                 const int* __restrict__ offs,
                                                 float* __restrict__ out) {
  const int m = blockIdx.x;
  const int o0 = offs[m];
  const int cnt = offs[m + 1] - o0;
  const int start = blockIdx.y * FPB;
  if (start >= cnt) return;
  const int nvalid = min(FPB, cnt - start);

  __shared__ __align__(16) __bf16 A_l[2 * 64 * FPB * 8];  // 64 KB
  __shared__ int rows_l[FPB];
  __shared__ float wmin_s[8][FPB];
  __shared__ int wcol_s[8][FPB];
  __shared__ float gmin_s[FPB];
  __shared__ int cnt_s[FPB];
  __shared__ int cand_s[FPB][32];

  const int tid = threadIdx.x;
  const int l = tid & 63;
  const int w = tid >> 6;          // 0..7
  const int ln = l & 31;
  const int lh = l >> 5;

  if (tid < FPB) rows_l[tid] = order[o0 + start + min(tid, nvalid - 1)];
  __syncthreads();

  // A staging role: thread -> row (tid&31), granule quad (tid>>5)*4..+3
  const int s_row = tid & 31;
  const int s_q = tid >> 5;                      // 0..15
  const float4* emb4 = (const float4*)emb;
  const size_t arow4 = (size_t)rows_l[s_row] * (E_DIM / 4);

  float4 pa[8];
  // stage chunk 0 (floats [0,512) of each row)
#pragma unroll
  for (int j = 0; j < 4; ++j) {
    pa[2 * j]     = emb4[arow4 + s_q * 8 + j * 2];
    pa[2 * j + 1] = emb4[arow4 + s_q * 8 + j * 2 + 1];
  }
#pragma unroll
  for (int j = 0; j < 4; ++j)
    *(bf16x8*)(A_l + ((s_q * 4 + j) * FPB + s_row) * 8) =
        cvt8(pa[2 * j], pa[2 * j + 1]);

  // B base pointers (swizzled bf16 region in d_out); wave w -> cg {2w, 2w+1}
  const char* bbase[2];
#pragma unroll
  for (int ct = 0; ct < 2; ++ct) {
    const int cg = w * 2 + ct;
    bbase[ct] = (const char*)out + (size_t)(m * 16 + cg) * 131072 + 2048 + l * 16;
  }
#define LOADB(ct, kb) (*(const bf16x8*)(bbase[ct] + (((kb) >> 1) << 12) + (((kb) & 1) << 10)))

  bf16x8 bR[8][2];                               // depth-8 ring
#pragma unroll
  for (int d = 0; d < 8; ++d)
#pragma unroll
    for (int ct = 0; ct < 2; ++ct) bR[d][ct] = LOADB(ct, d);

  floatx16 acc[2] = {};

  __syncthreads();                               // chunk-0 A ready (drain 1)

  // ---- chunk 0: issue chunk-1 A loads, then 32 MFMA steps ----
#pragma unroll
  for (int j = 0; j < 4; ++j) {
    pa[2 * j]     = emb4[arow4 + 128 + s_q * 8 + j * 2];
    pa[2 * j + 1] = emb4[arow4 + 128 + s_q * 8 + j * 2 + 1];
  }
#pragma unroll
  for (int jj = 0; jj < 32; ++jj) {
    const int kb = jj;
    const int p = kb & 7;
    const bf16x8 a0 = *(const bf16x8*)(A_l + ((jj * 2 + lh) * FPB + ln) * 8);
    acc[0] = __builtin_amdgcn_mfma_f32_32x32x16_bf16(a0, bR[p][0], acc[0], 0, 0, 0);
    acc[1] = __builtin_amdgcn_mfma_f32_32x32x16_bf16(a0, bR[p][1], acc[1], 0, 0, 0);
    bR[p][0] = LOADB(0, kb + 8);
    bR[p][1] = LOADB(1, kb + 8);
  }
  // write chunk-1 A into buffer 1
#pragma unroll
  for (int j = 0; j < 4; ++j)
    *(bf16x8*)(A_l + ((64 + s_q * 4 + j) * FPB + s_row) * 8) =
        cvt8(pa[2 * j], pa[2 * j + 1]);
  __syncthreads();                               // chunk-1 A ready (drain 2)

  // ---- chunk 1: 32 MFMA steps (refills while kb+8 < 64) ----
#pragma unroll
  for (int jj = 0; jj < 32; ++jj) {
    const int kb = 32 + jj;
    const int p = kb & 7;
    const bf16x8 a0 = *(const bf16x8*)(A_l + ((64 + jj * 2 + lh) * FPB + ln) * 8);
    acc[0] = __builtin_amdgcn_mfma_f32_32x32x16_bf16(a0, bR[p][0], acc[0], 0, 0, 0);
    acc[1] = __builtin_amdgcn_mfma_f32_32x32x16_bf16(a0, bR[p][1], acc[1], 0, 0, 0);
    if (kb + 8 < 64) {
      bR[p][0] = LOADB(0, kb + 8);
      bR[p][1] = LOADB(1, kb + 8);
    }
  }
#undef LOADB

  // ---- per-wave argmin (scores s = csq - 2*dot stay in regs) ----
  float cs[2];
#pragma unroll
  for (int ct = 0; ct < 2; ++ct)
    cs[ct] = (float)csq64[m * K_CLUST + w * 64 + ct * 32 + ln];

#pragma unroll
  for (int r = 0; r < 16; ++r) {
    const int fr = (r & 3) + 8 * (r >> 2) + 4 * lh;
    float bm = cs[0] - 2.0f * acc[0][r];
    int bc = w * 64 + ln;
    {
      const float s = cs[1] - 2.0f * acc[1][r];
      if (s < bm) { bm = s; bc = w * 64 + 32 + ln; }
    }
#pragma unroll
    for (int sh = 1; sh <= 16; sh <<= 1) {       // reduce within lane-half
      const float om = __shfl_xor(bm, sh, 64);
      const int oc = __shfl_xor(bc, sh, 64);
      if (om < bm || (om == bm && oc < bc)) { bm = om; bc = oc; }
    }
    if (ln == 0) { wmin_s[w][fr] = bm; wcol_s[w][fr] = bc; }
  }
  __syncthreads();

  if (tid < FPB) {                               // cross-wave min
    float g = wmin_s[0][tid];
    int gc = wcol_s[0][tid];
#pragma unroll
    for (int w2 = 1; w2 < 8; ++w2) {
      const float v = wmin_s[w2][tid];
      const int vc = wcol_s[w2][tid];
      if (v < g || (v == g && vc < gc)) { g = v; gc = vc; }
    }
    gmin_s[tid] = g;
    cnt_s[tid] = 0;
  }
  __syncthreads();

  // ---- candidate collection within eps = 3.0 ----
#pragma unroll
  for (int r = 0; r < 16; ++r) {
    const int fr = (r & 3) + 8 * (r >> 2) + 4 * lh;
    const float thr = gmin_s[fr] + 3.0f;
#pragma unroll
    for (int ct = 0; ct < 2; ++ct) {
      const float s = cs[ct] - 2.0f * acc[ct][r];
      if (s < thr) {
        const int ix = atomicAdd(&cnt_s[fr], 1);
        if (ix < 32) cand_s[fr][ix] = w * 64 + ct * 32 + ln;
      }
    }
  }
  __syncthreads();

  // ---- resolution: wave w -> frames w*4 .. w*4+3; exact fp64 recheck ----
  for (int i = 0; i < 4; ++i) {
    const int f = w * 4 + i;
    const int t = rows_l[f];
    const int n = min(cnt_s[f], 32);
    int code;
    if (n == 1) {
      code = cand_s[f][0];
    } else {
      float4 xv[4];
#pragma unroll
      for (int q = 0; q < 4; ++q) xv[q] = emb4[(size_t)t * (E_DIM / 4) + q * 64 + l];
      double bd = 1e300;
      int bi = 1 << 30;
      for (int j = 0; j < n; ++j) {
        const int cc = cand_s[f][j];
        const float4* crow4 = (const float4*)(cent + ((size_t)(m * K_CLUST + cc)) * E_DIM);
        double s = 0.0;
#pragma unroll
        for (int q = 0; q < 4; ++q) {
          const float4 cv = crow4[q * 64 + l];
          s += (double)xv[q].x * cv.x + (double)xv[q].y * cv.y +
               (double)xv[q].z * cv.z + (double)xv[q].w * cv.w;
        }
#pragma unroll
        for (int sh = 32; sh >= 1; sh >>= 1) s += __shfl_xor(s, sh, 64);
        const double d = csq64[m * K_CLUST + cc] - 2.0 * s;
        if (d < bd || (d == bd && cc < bi)) { bd = d; bi = cc; }
      }
      code = bi;
    }
    if (t >= 4096) {
      // rows >= 4096 never hold B panels: write the output row directly.
      const float4* crow = (const float4*)(cent + ((size_t)(m * K_CLUST + code)) * E_DIM);
      float4* drow = (float4*)(out + (size_t)t * E_DIM);
#pragma unroll
      for (int q = 0; q < 4; ++q) drow[q * 64 + l] = crow[q * 64 + l];
    } else if (l == 0) {
      *(int*)(out + (size_t)t * E_DIM) = code;   // col 0: no B overlap
    }
  }
}

// ---------------- K4: expand parked codes (t < 4096) -> output rows --------
__global__ __launch_bounds__(256) void k_gather(const float* __restrict__ cent,
                                                const int* __restrict__ midx,
                                                float* __restrict__ out) {
  const int t = blockIdx.x * 4 + (threadIdx.x >> 6);   // t in [0, 4096)
  const int l = threadIdx.x & 63;
  float* drow = out + (size_t)t * E_DIM;
  const int code = *(const int*)drow;            // read before overwrite (dep-ordered)
  const int m = midx[t];
  const float4* src = (const float4*)(cent + ((size_t)(m * K_CLUST + code)) * E_DIM);
  float4* dst = (float4*)drow;
#pragma unroll
  for (int q = 0; q < 4; ++q) dst[q * 64 + l] = src[q * 64 + l];
}

extern "C" void kernel_launch(void* const* d_in, const int* in_sizes, int n_in,
                              void* d_out, int out_size, void* d_ws, size_t ws_size,
                              hipStream_t stream) {
  const float* emb = (const float*)d_in[0];     // [1,T,E] fp32
  const float* cent = (const float*)d_in[1];    // [M,K,E] fp32
  const int* midx = (const int*)d_in[2];        // [T] int32
  float* out = (float*)d_out;                   // [1,T,E] fp32

  char* ws = (char*)d_ws;                       // ~100 KB
  double* csq64 = (double*)(ws + 0);
  int* hist = (int*)(ws + 32768);
  int* offs = (int*)(ws + 34816);
  int* order = (int*)(ws + 34880);

  hipMemsetAsync(csq64, 0, M_MODELS * K_CLUST * sizeof(double), stream);
  hipLaunchKernelGGL(k_cvt, dim3(512), dim3(256), 0, stream,
                     cent, out, csq64, midx, hist);
  hipLaunchKernelGGL(k_scatter, dim3(64), dim3(256), 0, stream, midx, hist, order, offs);
  hipLaunchKernelGGL(k_dist, dim3(M_MODELS, 80), dim3(512), 0, stream,
                     emb, cent, csq64, order, offs, out);
  hipLaunchKernelGGL(k_gather, dim3(4096 / 4), dim3(256), 0, stream,
                     cent, midx, out);
}